// Round 1
// baseline (194.354 us; speedup 1.0000x reference)
//
#include <hip/hip_runtime.h>
#include <stdint.h>

// ---------------------------------------------------------------------------
// HeteNet: bucketed-by-expert bf16 MFMA implementation.
// Tokens: 262144 (T=2048, A=128). x = [obs(64) | gp_sel(4)] padded to K=96.
// Expert chain 68->64->64->16, critic 68->64->64->1 fused in one pass.
// ws layout: hdr[32 ints] | bucket[262656 ints] | wp[56320 shorts frag-ready]
// ---------------------------------------------------------------------------

typedef float v4f __attribute__((ext_vector_type(4)));
typedef short v8s __attribute__((ext_vector_type(8)));

#define NTOK   262144
#define XS_STR 104   // LDS x stride (elems), 208 B = 13*16 (keeps 16B align)
#define HS_STR 136   // LDS h stride (elems), 272 B = 17*16
#define WP2_OFF 30720  // 60 frag-blocks * 512 shorts
#define WP3_OFF 51200  // + 40 * 512

static __device__ __forceinline__ short f2bf(float f) {
    union { float f; uint32_t u; } c; c.f = f;
    uint32_t u = c.u;
    uint32_t r = (u + 0x7FFFu + ((u >> 16) & 1u)) >> 16;
    return (short)r;
}

// ---------------- bucketing ----------------

__global__ void count_kernel(const int* __restrict__ hete, int* __restrict__ hdr) {
    __shared__ int wc[4][4];
    int tid = threadIdx.x, lane = tid & 63, w = tid >> 6;
    int i = blockIdx.x * 256 + tid;
    int e = hete[i];
#pragma unroll
    for (int t = 0; t < 4; t++) {
        unsigned long long m = __ballot(e == t);
        if (lane == 0) wc[w][t] = __popcll(m);
    }
    __syncthreads();
    if (tid < 4) {
        int s = wc[0][tid] + wc[1][tid] + wc[2][tid] + wc[3][tid];
        atomicAdd(&hdr[tid], s);
    }
}

__global__ void prefix_kernel(int* __restrict__ hdr, int* __restrict__ bucket) {
    __shared__ int sa[5], sc[4];
    int tid = threadIdx.x;
    if (tid == 0) {
        int a = 0, ts = 0;
        for (int e = 0; e < 4; e++) {
            int c = hdr[e];
            sc[e] = c;
            sa[e] = a;
            hdr[4 + e]  = a;  // scatter cursor
            hdr[8 + e]  = a;  // astart
            hdr[13 + e] = ts; // tileStart
            int tiles = (c + 127) >> 7;
            a  += tiles << 7;
            ts += tiles;
        }
        sa[4]   = a;
        hdr[12] = a;
        hdr[17] = ts; // total tiles
    }
    __syncthreads();
    for (int e = 0; e < 4; e++) {
        int start = sa[e] + sc[e];
        int end   = sa[e + 1];
        for (int i = start + tid; i < end; i += 256) bucket[i] = -1;
    }
}

__global__ void scatter_kernel(const int* __restrict__ hete, int* __restrict__ hdr,
                               int* __restrict__ bucket) {
    __shared__ int wc[4][4], wb[4][4];
    int tid = threadIdx.x, lane = tid & 63, w = tid >> 6;
    int i = blockIdx.x * 256 + tid;
    int e = hete[i];
    unsigned long long lt = (1ull << lane) - 1ull;
    int rank = 0;
#pragma unroll
    for (int t = 0; t < 4; t++) {
        unsigned long long m = __ballot(e == t);
        if (lane == 0) wc[w][t] = __popcll(m);
        if (e == t) rank = __popcll(m & lt);
    }
    __syncthreads();
    if (tid < 4) {
        int t = tid, tot = 0;
#pragma unroll
        for (int ww = 0; ww < 4; ww++) tot += wc[ww][t];
        int base = atomicAdd(&hdr[4 + t], tot);
#pragma unroll
        for (int ww = 0; ww < 4; ww++) { int c = wc[ww][t]; wb[ww][t] = base; base += c; }
    }
    __syncthreads();
    bucket[wb[w][e] + rank] = i;
}

// ---------------- weight prep: B-fragment-ready bf16 layout ----------------
// frag-block = 64 lanes x 8 bf16: lane holds B[k][n], n = base_n + (lane&15),
// k = base_k + (lane>>4)*8 + j.  L1 ids: (e*3+ks)*4+nt (e=4 critic), 60 blocks.
// L2 ids: (e*2+ks)*4+nt, 40 blocks. L3: e*2+ks (experts, N=16), 8..9 critic.

__global__ void prep_kernel(const float* __restrict__ W1, const float* __restrict__ cW1,
                            const float* __restrict__ W2, const float* __restrict__ cW2,
                            const float* __restrict__ W3, const float* __restrict__ cW3,
                            short* __restrict__ wp) {
    int b = blockIdx.x, lane = threadIdx.x;
    int nl = lane & 15, quad = lane >> 4;
    short frag[8];
    if (b < 60) {
        int e = b / 12, rem = b % 12, ks = rem / 4, nt = rem % 4;
        int n = nt * 16 + nl;
#pragma unroll
        for (int j = 0; j < 8; j++) {
            int k = ks * 32 + quad * 8 + j;
            float v = 0.f;
            if (k < 68) v = (e < 4) ? W1[(e * 68 + k) * 64 + n] : cW1[k * 64 + n];
            frag[j] = f2bf(v);
        }
    } else if (b < 100) {
        int u = b - 60, e = u / 8, ks = (u % 8) / 4, nt = u % 4;
        int n = nt * 16 + nl;
#pragma unroll
        for (int j = 0; j < 8; j++) {
            int k = ks * 32 + quad * 8 + j;
            frag[j] = f2bf((e < 4) ? W2[(e * 64 + k) * 64 + n] : cW2[k * 64 + n]);
        }
    } else {
        int u = b - 100;
#pragma unroll
        for (int j = 0; j < 8; j++) {
            int ks = (u < 8) ? (u & 1) : (u - 8);
            int k  = ks * 32 + quad * 8 + j;
            float v;
            if (u < 8) { int ee = u >> 1; v = W3[(ee * 64 + k) * 16 + nl]; }
            else       { v = (nl == 0) ? cW3[k] : 0.f; }
            frag[j] = f2bf(v);
        }
    }
    v8s pk = { frag[0], frag[1], frag[2], frag[3], frag[4], frag[5], frag[6], frag[7] };
    *(v8s*)(wp + (size_t)b * 512 + lane * 8) = pk;
}

// ---------------- main fused kernel ----------------

__global__ __launch_bounds__(256) void main_kernel(
    const float* __restrict__ obs, const float* __restrict__ gp,
    const int* __restrict__ bucket, const int* __restrict__ hdr,
    const short* __restrict__ wp,
    const float* __restrict__ b1, const float* __restrict__ b2, const float* __restrict__ b3,
    const float* __restrict__ cb1, const float* __restrict__ cb2, const float* __restrict__ cb3,
    float* __restrict__ out)
{
    __shared__ __align__(16) short xs[128 * XS_STR];
    __shared__ __align__(16) short hs[128 * HS_STR];
    __shared__ int tokL[128];

    int b = blockIdx.x;
    int total = hdr[17];
    if (b >= total) return;
    int e = 3;
    if      (b < hdr[14]) e = 0;
    else if (b < hdr[15]) e = 1;
    else if (b < hdr[16]) e = 2;
    int slot0 = hdr[8 + e] + (b - hdr[13 + e]) * 128;

    int tid = threadIdx.x, lane = tid & 63, w = tid >> 6;
    int ml = lane & 15, quad = lane >> 4;

    if (tid < 128) tokL[tid] = bucket[slot0 + tid];

    // --- stage x tile: 2 threads per row (32 cols each), row stride XS_STR ---
    {
        int r = tid >> 1, hh = tid & 1;
        int tk = bucket[slot0 + r];
        v8s z = { 0, 0, 0, 0, 0, 0, 0, 0 };
        if (tk >= 0) {
            const float4* src = (const float4*)(obs + (size_t)tk * 64 + hh * 32);
#pragma unroll
            for (int t = 0; t < 4; t++) {
                float4 f0 = src[2 * t], f1 = src[2 * t + 1];
                v8s pk = { f2bf(f0.x), f2bf(f0.y), f2bf(f0.z), f2bf(f0.w),
                           f2bf(f1.x), f2bf(f1.y), f2bf(f1.z), f2bf(f1.w) };
                *(v8s*)&xs[r * XS_STR + hh * 32 + t * 8] = pk;
            }
            if (hh) {
                const float* g = gp + (size_t)(tk >> 7) * 4;
                v8s pg = { f2bf(g[0]), f2bf(g[1]), f2bf(g[2]), f2bf(g[3]), 0, 0, 0, 0 };
                *(v8s*)&xs[r * XS_STR + 64] = pg;
                *(v8s*)&xs[r * XS_STR + 72] = z;
                *(v8s*)&xs[r * XS_STR + 80] = z;
                *(v8s*)&xs[r * XS_STR + 88] = z;
            }
        } else {
#pragma unroll
            for (int t = 0; t < 4; t++) *(v8s*)&xs[r * XS_STR + hh * 32 + t * 8] = z;
            if (hh) {
                *(v8s*)&xs[r * XS_STR + 64] = z;
                *(v8s*)&xs[r * XS_STR + 72] = z;
                *(v8s*)&xs[r * XS_STR + 80] = z;
                *(v8s*)&xs[r * XS_STR + 88] = z;
            }
        }
    }
    __syncthreads();

    // --- layer 1: [128 x 96] @ [96 x 64]  (expert + critic fused) ---
    v4f accE[8], accC[8];
#pragma unroll
    for (int m = 0; m < 8; m++) { accE[m] = (v4f){0,0,0,0}; accC[m] = (v4f){0,0,0,0}; }
#pragma unroll
    for (int ks = 0; ks < 3; ks++) {
        v8s bE = *(const v8s*)(wp + (size_t)((e * 3 + ks) * 4 + w) * 512 + lane * 8);
        v8s bC = *(const v8s*)(wp + (size_t)((12 + ks) * 4 + w) * 512 + lane * 8);
#pragma unroll
        for (int m = 0; m < 8; m++) {
            v8s a = *(const v8s*)&xs[(m * 16 + ml) * XS_STR + ks * 32 + quad * 8];
            accE[m] = __builtin_amdgcn_mfma_f32_16x16x32_bf16(a, bE, accE[m], 0, 0, 0);
            accC[m] = __builtin_amdgcn_mfma_f32_16x16x32_bf16(a, bC, accC[m], 0, 0, 0);
        }
    }
    {
        float bE1 = b1[e * 64 + w * 16 + ml], bC1 = cb1[w * 16 + ml];
#pragma unroll
        for (int m = 0; m < 8; m++)
#pragma unroll
            for (int rr = 0; rr < 4; rr++) {
                int row = m * 16 + quad * 4 + rr;
                hs[row * HS_STR + w * 16 + ml]      = f2bf(fmaxf(accE[m][rr] + bE1, 0.f));
                hs[row * HS_STR + 64 + w * 16 + ml] = f2bf(fmaxf(accC[m][rr] + bC1, 0.f));
            }
    }
    __syncthreads();

    // --- layer 2: [128 x 64] @ [64 x 64] for both nets ---
    v4f acc2E[8], acc2C[8];
#pragma unroll
    for (int m = 0; m < 8; m++) { acc2E[m] = (v4f){0,0,0,0}; acc2C[m] = (v4f){0,0,0,0}; }
#pragma unroll
    for (int ks = 0; ks < 2; ks++) {
        v8s bE = *(const v8s*)(wp + WP2_OFF + (size_t)((e * 2 + ks) * 4 + w) * 512 + lane * 8);
        v8s bC = *(const v8s*)(wp + WP2_OFF + (size_t)((8 + ks) * 4 + w) * 512 + lane * 8);
#pragma unroll
        for (int m = 0; m < 8; m++) {
            v8s aE = *(const v8s*)&hs[(m * 16 + ml) * HS_STR + ks * 32 + quad * 8];
            v8s aC = *(const v8s*)&hs[(m * 16 + ml) * HS_STR + 64 + ks * 32 + quad * 8];
            acc2E[m] = __builtin_amdgcn_mfma_f32_16x16x32_bf16(aE, bE, acc2E[m], 0, 0, 0);
            acc2C[m] = __builtin_amdgcn_mfma_f32_16x16x32_bf16(aC, bC, acc2C[m], 0, 0, 0);
        }
    }
    __syncthreads();  // all h1 reads complete before overwrite
    {
        float bE2 = b2[e * 64 + w * 16 + ml], bC2 = cb2[w * 16 + ml];
#pragma unroll
        for (int m = 0; m < 8; m++)
#pragma unroll
            for (int rr = 0; rr < 4; rr++) {
                int row = m * 16 + quad * 4 + rr;
                hs[row * HS_STR + w * 16 + ml]      = f2bf(fmaxf(acc2E[m][rr] + bE2, 0.f));
                hs[row * HS_STR + 64 + w * 16 + ml] = f2bf(fmaxf(acc2C[m][rr] + bC2, 0.f));
            }
    }
    __syncthreads();

    // --- layer 3: expert [128x64]@[64x16], critic value (padded N=16) ---
    v4f accL[2], accV[2];
#pragma unroll
    for (int mm = 0; mm < 2; mm++) { accL[mm] = (v4f){0,0,0,0}; accV[mm] = (v4f){0,0,0,0}; }
#pragma unroll
    for (int ks = 0; ks < 2; ks++) {
        v8s bW = *(const v8s*)(wp + WP3_OFF + (size_t)(e * 2 + ks) * 512 + lane * 8);
        v8s bV = *(const v8s*)(wp + WP3_OFF + (size_t)(8 + ks) * 512 + lane * 8);
#pragma unroll
        for (int mm = 0; mm < 2; mm++) {
            v8s aE = *(const v8s*)&hs[((2 * w + mm) * 16 + ml) * HS_STR + ks * 32 + quad * 8];
            v8s aC = *(const v8s*)&hs[((2 * w + mm) * 16 + ml) * HS_STR + 64 + ks * 32 + quad * 8];
            accL[mm] = __builtin_amdgcn_mfma_f32_16x16x32_bf16(aE, bW, accL[mm], 0, 0, 0);
            accV[mm] = __builtin_amdgcn_mfma_f32_16x16x32_bf16(aC, bV, accV[mm], 0, 0, 0);
        }
    }

    // --- epilogue: out[token][0..15] = logits, out[token][16] = value ---
    {
        float b3v = b3[e * 16 + ml], cb3v = cb3[0];
#pragma unroll
        for (int mm = 0; mm < 2; mm++)
#pragma unroll
            for (int rr = 0; rr < 4; rr++) {
                int row = (2 * w + mm) * 16 + quad * 4 + rr;
                int tk = tokL[row];
                if (tk >= 0) {
                    float* o = out + (size_t)tk * 17;
                    o[ml] = accL[mm][rr] + b3v;
                    if (ml == 0) o[16] = accV[mm][rr] + cb3v;
                }
            }
    }
}

// ---------------------------------------------------------------------------

extern "C" void kernel_launch(void* const* d_in, const int* in_sizes, int n_in,
                              void* d_out, int out_size, void* d_ws, size_t ws_size,
                              hipStream_t stream) {
    const float* obs = (const float*)d_in[0];
    const int*  hete = (const int*)d_in[1];
    const float* gp  = (const float*)d_in[2];
    const float* W1  = (const float*)d_in[3];
    const float* b1  = (const float*)d_in[4];
    const float* W2  = (const float*)d_in[5];
    const float* b2  = (const float*)d_in[6];
    const float* W3  = (const float*)d_in[7];
    const float* b3  = (const float*)d_in[8];
    const float* cW1 = (const float*)d_in[9];
    const float* cb1 = (const float*)d_in[10];
    const float* cW2 = (const float*)d_in[11];
    const float* cb2 = (const float*)d_in[12];
    const float* cW3 = (const float*)d_in[13];
    const float* cb3 = (const float*)d_in[14];
    float* out = (float*)d_out;

    int*   hdr    = (int*)d_ws;
    int*   bucket = hdr + 32;                 // 262656 ints
    short* wp     = (short*)(bucket + 262656); // 56320 shorts (112640 B)

    hipMemsetAsync(hdr, 0, 128, stream);
    count_kernel  <<<1024, 256, 0, stream>>>(hete, hdr);
    prefix_kernel <<<1,    256, 0, stream>>>(hdr, bucket);
    scatter_kernel<<<1024, 256, 0, stream>>>(hete, hdr, bucket);
    prep_kernel   <<<110,   64, 0, stream>>>(W1, cW1, W2, cW2, W3, cW3, wp);
    main_kernel   <<<2051, 256, 0, stream>>>(obs, gp, bucket, hdr, wp,
                                             b1, b2, b3, cb1, cb2, cb3, out);
}

// Round 2
// 159.738 us; speedup vs baseline: 1.2167x; 1.2167x over previous
//
#include <hip/hip_runtime.h>
#include <stdint.h>

// ---------------------------------------------------------------------------
// HeteNet: bucketed-by-expert bf16 MFMA implementation. Round 2.
// - No global atomics in bucketing (per-block counts + 1-block scan + bases).
// - Union LDS buffer in main kernel (xs dead after L1) -> 4 blocks/CU.
// ws layout: hdr[32] | bucket[262656] | cnt[1024] | bb[1024] | wp[56320 shorts]
// ---------------------------------------------------------------------------

typedef float v4f __attribute__((ext_vector_type(4)));
typedef short v8s __attribute__((ext_vector_type(8)));

#define XS_STR 104   // LDS x stride (elems), 208 B
#define HS_STR 136   // LDS h stride (elems), 272 B
#define WP2_OFF 30720  // 60 frag-blocks * 512 shorts
#define WP3_OFF 51200  // + 40 * 512

static __device__ __forceinline__ short f2bf(float f) {
    union { float f; uint32_t u; } c; c.f = f;
    uint32_t u = c.u;
    uint32_t r = (u + 0x7FFFu + ((u >> 16) & 1u)) >> 16;
    return (short)r;
}

// ---------------- bucketing (atomic-free globally) ----------------

// 256 blocks x 256 thr, each block counts 1024 consecutive tokens.
__global__ void count_kernel(const int* __restrict__ hete, int* __restrict__ cnt) {
    __shared__ int wc[4][4];
    int tid = threadIdx.x, lane = tid & 63, w = tid >> 6;
    int base = blockIdx.x * 1024;
    int lc[4] = {0, 0, 0, 0};
#pragma unroll
    for (int c = 0; c < 4; c++) {
        int e = hete[base + c * 256 + tid];
#pragma unroll
        for (int t = 0; t < 4; t++) {
            unsigned long long m = __ballot(e == t);
            if (lane == 0) lc[t] += __popcll(m);
        }
    }
    if (lane == 0)
#pragma unroll
        for (int t = 0; t < 4; t++) wc[w][t] = lc[t];
    __syncthreads();
    if (tid < 4)
        cnt[blockIdx.x * 4 + tid] = wc[0][tid] + wc[1][tid] + wc[2][tid] + wc[3][tid];
}

// single block: scan per-block counts -> segment starts, per-block bases, pads
__global__ void prefix_kernel(const int* __restrict__ cnt, int* __restrict__ hdr,
                              int* __restrict__ bb, int* __restrict__ bucket) {
    __shared__ int s[4][256];
    __shared__ int sa[5], sC[4];
    int tid = threadIdx.x;
    int c0[4];
#pragma unroll
    for (int t = 0; t < 4; t++) { c0[t] = cnt[tid * 4 + t]; s[t][tid] = c0[t]; }
    __syncthreads();
    for (int off = 1; off < 256; off <<= 1) {
        int v[4];
#pragma unroll
        for (int t = 0; t < 4; t++) v[t] = (tid >= off) ? s[t][tid - off] : 0;
        __syncthreads();
#pragma unroll
        for (int t = 0; t < 4; t++) s[t][tid] += v[t];
        __syncthreads();
    }
    if (tid == 0) {
        int a = 0, ts = 0;
        for (int e = 0; e < 4; e++) {
            int c = s[e][255];
            sC[e] = c;
            sa[e] = a;
            hdr[8 + e]  = a;   // segment start (aligned)
            hdr[13 + e] = ts;  // tile start
            int tiles = (c + 127) >> 7;
            a  += tiles << 7;
            ts += tiles;
        }
        sa[4]   = a;
        hdr[12] = a;
        hdr[17] = ts;  // total tiles
    }
    __syncthreads();
#pragma unroll
    for (int t = 0; t < 4; t++) bb[tid * 4 + t] = sa[t] + s[t][tid] - c0[t];
    for (int e = 0; e < 4; e++) {
        int start = sa[e] + sC[e], end = sa[e + 1];
        for (int i = start + tid; i < end; i += 256) bucket[i] = -1;
    }
}

// 256 blocks; LDS cursors only (no global atomics)
__global__ void scatter_kernel(const int* __restrict__ hete, const int* __restrict__ bb,
                               int* __restrict__ bucket) {
    __shared__ int cur[4];
    int tid = threadIdx.x, lane = tid & 63;
    if (tid < 4) cur[tid] = bb[blockIdx.x * 4 + tid];
    __syncthreads();
    unsigned long long lt = (1ull << lane) - 1ull;
#pragma unroll
    for (int c = 0; c < 4; c++) {
        int i = blockIdx.x * 1024 + c * 256 + tid;
        int e = hete[i];
        int slot = 0;
#pragma unroll
        for (int t = 0; t < 4; t++) {
            unsigned long long m = __ballot(e == t);
            int n = __popcll(m);
            int wb = 0;
            if (lane == 0 && n) wb = atomicAdd(&cur[t], n);
            wb = __shfl(wb, 0);
            if (e == t) slot = wb + __popcll(m & lt);
        }
        bucket[slot] = i;
    }
}

// ---------------- weight prep: B-fragment-ready bf16 layout ----------------
__global__ void prep_kernel(const float* __restrict__ W1, const float* __restrict__ cW1,
                            const float* __restrict__ W2, const float* __restrict__ cW2,
                            const float* __restrict__ W3, const float* __restrict__ cW3,
                            short* __restrict__ wp) {
    int b = blockIdx.x, lane = threadIdx.x;
    int nl = lane & 15, quad = lane >> 4;
    short frag[8];
    if (b < 60) {
        int e = b / 12, rem = b % 12, ks = rem / 4, nt = rem % 4;
        int n = nt * 16 + nl;
#pragma unroll
        for (int j = 0; j < 8; j++) {
            int k = ks * 32 + quad * 8 + j;
            float v = 0.f;
            if (k < 68) v = (e < 4) ? W1[(e * 68 + k) * 64 + n] : cW1[k * 64 + n];
            frag[j] = f2bf(v);
        }
    } else if (b < 100) {
        int u = b - 60, e = u / 8, ks = (u % 8) / 4, nt = u % 4;
        int n = nt * 16 + nl;
#pragma unroll
        for (int j = 0; j < 8; j++) {
            int k = ks * 32 + quad * 8 + j;
            frag[j] = f2bf((e < 4) ? W2[(e * 64 + k) * 64 + n] : cW2[k * 64 + n]);
        }
    } else {
        int u = b - 100;
#pragma unroll
        for (int j = 0; j < 8; j++) {
            int ks = (u < 8) ? (u & 1) : (u - 8);
            int k  = ks * 32 + quad * 8 + j;
            float v;
            if (u < 8) { int ee = u >> 1; v = W3[(ee * 64 + k) * 16 + nl]; }
            else       { v = (nl == 0) ? cW3[k] : 0.f; }
            frag[j] = f2bf(v);
        }
    }
    v8s pk = { frag[0], frag[1], frag[2], frag[3], frag[4], frag[5], frag[6], frag[7] };
    *(v8s*)(wp + (size_t)b * 512 + lane * 8) = pk;
}

// ---------------- main fused kernel ----------------

__global__ __launch_bounds__(256) void main_kernel(
    const float* __restrict__ obs, const float* __restrict__ gp,
    const int* __restrict__ bucket, const int* __restrict__ hdr,
    const short* __restrict__ wp,
    const float* __restrict__ b1, const float* __restrict__ b2, const float* __restrict__ b3,
    const float* __restrict__ cb1, const float* __restrict__ cb2, const float* __restrict__ cb3,
    float* __restrict__ out)
{
    // union buffer: xs phase uses stride XS_STR (13312 shorts),
    // hs phase uses stride HS_STR (17408 shorts). Phases barrier-separated.
    __shared__ __align__(16) short buf[128 * HS_STR];
    __shared__ int tokL[128];
    short* xs = buf;
    short* hs = buf;

    int b = blockIdx.x;
    int total = hdr[17];
    if (b >= total) return;
    int e = 3;
    if      (b < hdr[14]) e = 0;
    else if (b < hdr[15]) e = 1;
    else if (b < hdr[16]) e = 2;
    int slot0 = hdr[8 + e] + (b - hdr[13 + e]) * 128;

    int tid = threadIdx.x, lane = tid & 63, w = tid >> 6;
    int ml = lane & 15, quad = lane >> 4;

    if (tid < 128) tokL[tid] = bucket[slot0 + tid];

    // --- stage x tile: 2 threads per row (32 cols each) ---
    {
        int r = tid >> 1, hh = tid & 1;
        int tk = bucket[slot0 + r];
        v8s z = { 0, 0, 0, 0, 0, 0, 0, 0 };
        if (tk >= 0) {
            const float4* src = (const float4*)(obs + (size_t)tk * 64 + hh * 32);
#pragma unroll
            for (int t = 0; t < 4; t++) {
                float4 f0 = src[2 * t], f1 = src[2 * t + 1];
                v8s pk = { f2bf(f0.x), f2bf(f0.y), f2bf(f0.z), f2bf(f0.w),
                           f2bf(f1.x), f2bf(f1.y), f2bf(f1.z), f2bf(f1.w) };
                *(v8s*)&xs[r * XS_STR + hh * 32 + t * 8] = pk;
            }
            if (hh) {
                const float* g = gp + (size_t)(tk >> 7) * 4;
                v8s pg = { f2bf(g[0]), f2bf(g[1]), f2bf(g[2]), f2bf(g[3]), 0, 0, 0, 0 };
                *(v8s*)&xs[r * XS_STR + 64] = pg;
                *(v8s*)&xs[r * XS_STR + 72] = z;
                *(v8s*)&xs[r * XS_STR + 80] = z;
                *(v8s*)&xs[r * XS_STR + 88] = z;
            }
        } else {
#pragma unroll
            for (int t = 0; t < 4; t++) *(v8s*)&xs[r * XS_STR + hh * 32 + t * 8] = z;
            if (hh) {
                *(v8s*)&xs[r * XS_STR + 64] = z;
                *(v8s*)&xs[r * XS_STR + 72] = z;
                *(v8s*)&xs[r * XS_STR + 80] = z;
                *(v8s*)&xs[r * XS_STR + 88] = z;
            }
        }
    }
    __syncthreads();

    // --- layer 1: [128 x 96] @ [96 x 64]  (expert + critic fused) ---
    v4f accE[8], accC[8];
#pragma unroll
    for (int m = 0; m < 8; m++) { accE[m] = (v4f){0,0,0,0}; accC[m] = (v4f){0,0,0,0}; }
#pragma unroll
    for (int ks = 0; ks < 3; ks++) {
        v8s bE = *(const v8s*)(wp + (size_t)((e * 3 + ks) * 4 + w) * 512 + lane * 8);
        v8s bC = *(const v8s*)(wp + (size_t)((12 + ks) * 4 + w) * 512 + lane * 8);
#pragma unroll
        for (int m = 0; m < 8; m++) {
            v8s a = *(const v8s*)&xs[(m * 16 + ml) * XS_STR + ks * 32 + quad * 8];
            accE[m] = __builtin_amdgcn_mfma_f32_16x16x32_bf16(a, bE, accE[m], 0, 0, 0);
            accC[m] = __builtin_amdgcn_mfma_f32_16x16x32_bf16(a, bC, accC[m], 0, 0, 0);
        }
    }
    __syncthreads();  // xs reads complete before hs overwrites (union buffer)
    {
        float bE1 = b1[e * 64 + w * 16 + ml], bC1 = cb1[w * 16 + ml];
#pragma unroll
        for (int m = 0; m < 8; m++)
#pragma unroll
            for (int rr = 0; rr < 4; rr++) {
                int row = m * 16 + quad * 4 + rr;
                hs[row * HS_STR + w * 16 + ml]      = f2bf(fmaxf(accE[m][rr] + bE1, 0.f));
                hs[row * HS_STR + 64 + w * 16 + ml] = f2bf(fmaxf(accC[m][rr] + bC1, 0.f));
            }
    }
    __syncthreads();

    // --- layer 2: [128 x 64] @ [64 x 64] for both nets ---
    v4f acc2E[8], acc2C[8];
#pragma unroll
    for (int m = 0; m < 8; m++) { acc2E[m] = (v4f){0,0,0,0}; acc2C[m] = (v4f){0,0,0,0}; }
#pragma unroll
    for (int ks = 0; ks < 2; ks++) {
        v8s bE = *(const v8s*)(wp + WP2_OFF + (size_t)((e * 2 + ks) * 4 + w) * 512 + lane * 8);
        v8s bC = *(const v8s*)(wp + WP2_OFF + (size_t)((8 + ks) * 4 + w) * 512 + lane * 8);
#pragma unroll
        for (int m = 0; m < 8; m++) {
            v8s aE = *(const v8s*)&hs[(m * 16 + ml) * HS_STR + ks * 32 + quad * 8];
            v8s aC = *(const v8s*)&hs[(m * 16 + ml) * HS_STR + 64 + ks * 32 + quad * 8];
            acc2E[m] = __builtin_amdgcn_mfma_f32_16x16x32_bf16(aE, bE, acc2E[m], 0, 0, 0);
            acc2C[m] = __builtin_amdgcn_mfma_f32_16x16x32_bf16(aC, bC, acc2C[m], 0, 0, 0);
        }
    }
    __syncthreads();  // all h1 reads complete before overwrite
    {
        float bE2 = b2[e * 64 + w * 16 + ml], bC2 = cb2[w * 16 + ml];
#pragma unroll
        for (int m = 0; m < 8; m++)
#pragma unroll
            for (int rr = 0; rr < 4; rr++) {
                int row = m * 16 + quad * 4 + rr;
                hs[row * HS_STR + w * 16 + ml]      = f2bf(fmaxf(acc2E[m][rr] + bE2, 0.f));
                hs[row * HS_STR + 64 + w * 16 + ml] = f2bf(fmaxf(acc2C[m][rr] + bC2, 0.f));
            }
    }
    __syncthreads();

    // --- layer 3: expert [128x64]@[64x16], critic value (padded N=16) ---
    v4f accL[2], accV[2];
#pragma unroll
    for (int mm = 0; mm < 2; mm++) { accL[mm] = (v4f){0,0,0,0}; accV[mm] = (v4f){0,0,0,0}; }
#pragma unroll
    for (int ks = 0; ks < 2; ks++) {
        v8s bW = *(const v8s*)(wp + WP3_OFF + (size_t)(e * 2 + ks) * 512 + lane * 8);
        v8s bV = *(const v8s*)(wp + WP3_OFF + (size_t)(8 + ks) * 512 + lane * 8);
#pragma unroll
        for (int mm = 0; mm < 2; mm++) {
            v8s aE = *(const v8s*)&hs[((2 * w + mm) * 16 + ml) * HS_STR + ks * 32 + quad * 8];
            v8s aC = *(const v8s*)&hs[((2 * w + mm) * 16 + ml) * HS_STR + 64 + ks * 32 + quad * 8];
            accL[mm] = __builtin_amdgcn_mfma_f32_16x16x32_bf16(aE, bW, accL[mm], 0, 0, 0);
            accV[mm] = __builtin_amdgcn_mfma_f32_16x16x32_bf16(aC, bV, accV[mm], 0, 0, 0);
        }
    }

    // --- epilogue: out[token][0..15] = logits, out[token][16] = value ---
    {
        float b3v = b3[e * 16 + ml], cb3v = cb3[0];
#pragma unroll
        for (int mm = 0; mm < 2; mm++)
#pragma unroll
            for (int rr = 0; rr < 4; rr++) {
                int row = (2 * w + mm) * 16 + quad * 4 + rr;
                int tk = tokL[row];
                if (tk >= 0) {
                    float* o = out + (size_t)tk * 17;
                    o[ml] = accL[mm][rr] + b3v;
                    if (ml == 0) o[16] = accV[mm][rr] + cb3v;
                }
            }
    }
}

// ---------------------------------------------------------------------------

extern "C" void kernel_launch(void* const* d_in, const int* in_sizes, int n_in,
                              void* d_out, int out_size, void* d_ws, size_t ws_size,
                              hipStream_t stream) {
    const float* obs = (const float*)d_in[0];
    const int*  hete = (const int*)d_in[1];
    const float* gp  = (const float*)d_in[2];
    const float* W1  = (const float*)d_in[3];
    const float* b1  = (const float*)d_in[4];
    const float* W2  = (const float*)d_in[5];
    const float* b2  = (const float*)d_in[6];
    const float* W3  = (const float*)d_in[7];
    const float* b3  = (const float*)d_in[8];
    const float* cW1 = (const float*)d_in[9];
    const float* cb1 = (const float*)d_in[10];
    const float* cW2 = (const float*)d_in[11];
    const float* cb2 = (const float*)d_in[12];
    const float* cW3 = (const float*)d_in[13];
    const float* cb3 = (const float*)d_in[14];
    float* out = (float*)d_out;

    int*   hdr    = (int*)d_ws;
    int*   bucket = hdr + 32;                  // 262656 ints
    int*   cnt    = bucket + 262656;           // 1024 ints
    int*   bb     = cnt + 1024;                // 1024 ints
    short* wp     = (short*)(bb + 1024);       // 56320 shorts

    count_kernel  <<<256, 256, 0, stream>>>(hete, cnt);
    prefix_kernel <<<1,   256, 0, stream>>>(cnt, hdr, bb, bucket);
    scatter_kernel<<<256, 256, 0, stream>>>(hete, bb, bucket);
    prep_kernel   <<<110,  64, 0, stream>>>(W1, cW1, W2, cW2, W3, cW3, wp);
    main_kernel   <<<2051, 256, 0, stream>>>(obs, gp, bucket, hdr, wp,
                                             b1, b2, b3, cb1, cb2, cb3, out);
}